// Round 12
// baseline (435.051 us; speedup 1.0000x reference)
//
#include <hip/hip_runtime.h>
#include <cstdint>
#include <cstddef>

// ---------------------------------------------------------------------------
// L4maAttention, fp16 pipeline (round 12):
//   cvt_all -> gemm_fused<0> (384 GEMM + 128 cache-conv blocks = 512, 2/CU) ->
//   aux2 (Wo cvt + RoPE q/k) ->
//   attn_part (KV-split z=0..3, KVBLK=32, 32 q/wave, 4 blocks/CU,
//              lane-local softmax, x16-MFMA PV + ones-MFMA lsum) ->
//   combine (4 partials, in-place into partial 0) -> O-proj GEMM -> fp32.
// ---------------------------------------------------------------------------

typedef _Float16 f16;
typedef f16 f16x8 __attribute__((ext_vector_type(8)));
typedef f16 f16x4 __attribute__((ext_vector_type(4)));
typedef float f32x4 __attribute__((ext_vector_type(4)));

#define HIDN 4096
#define LCTX 3072
#define PASTN 2048
#define QK_SCALE_LOG2 0.12753102734366334f
#define RESC_THR 11.54f

__device__ __forceinline__ f32x4 mfma16(f16x8 a, f16x8 b, f32x4 c) {
    return __builtin_amdgcn_mfma_f32_16x16x32_f16(a, b, c, 0, 0, 0);
}
__device__ __forceinline__ f32x4 mfma16k16(f16x4 a, f16x4 b, f32x4 c) {
    return __builtin_amdgcn_mfma_f32_16x16x16f16(a, b, c, 0, 0, 0);
}

__device__ __forceinline__ void gl_lds16(const void* g, void* l) {
    auto gp = (const __attribute__((address_space(1))) unsigned int*)(uintptr_t)g;
    auto lp = (__attribute__((address_space(3))) unsigned int*)(uintptr_t)l;
    __builtin_amdgcn_global_load_lds(gp, lp, 16, 0, 0);
}

__device__ __forceinline__ uint32_t lds_lo(const void* p) {
    return (uint32_t)(uintptr_t)p;
}

#define TRRD(dst, va, OFF) \
    asm volatile("ds_read_b64_tr_b16 %0, %1 offset:" #OFF : "=v"(dst) : "v"(va))
#define WAITL(N) \
    asm volatile("s_waitcnt lgkmcnt(" #N ")" ::: "memory"); \
    __builtin_amdgcn_sched_barrier(0)

// ---------------------------------------------------------------------------
// cvt_all: hidden (1M f4) + Wq (4M) + Wk (1M) + Wv (1M) = 7,340,032 = 28672x256
// ---------------------------------------------------------------------------
__global__ void cvt_all(const float* __restrict__ hidden, const float* __restrict__ Wq,
                        const float* __restrict__ Wk, const float* __restrict__ Wv,
                        f16* __restrict__ h16, f16* __restrict__ w16)
{
    int i = blockIdx.x * 256 + threadIdx.x;
    const float* src; f16* dst; int off;
    if (i < 1048576)      { src = hidden; dst = h16; off = i; }
    else if (i < 5242880) { src = Wq; dst = w16; off = i - 1048576; }
    else if (i < 6291456) { src = Wk; dst = w16 + (size_t)4096 * 4096; off = i - 5242880; }
    else                  { src = Wv; dst = w16 + (size_t)5120 * 4096; off = i - 6291456; }
    f32x4 v = *(const f32x4*)(src + (size_t)off * 4);
    f16x4 h;
#pragma unroll
    for (int j = 0; j < 4; j++) h[j] = (f16)v[j];
    *(f16x4*)(dst + (size_t)off * 4) = h;
}

// ---------------------------------------------------------------------------
// GEMM (+fused cache_conv for EPI 0): C[M,N] = A[M,K] @ B[N,K]^T, fp16.
// EPI 0: grid 512: blocks 0..383 GEMM (48 x 8 tiles), 384..511 cache convert
//        (32 grid-stride passes each) -> 2 blocks/CU exact.
// EPI 1: grid 256 (32 x 8 tiles), fp32 C.
// ---------------------------------------------------------------------------
template <int EPI>
__global__ __launch_bounds__(256, 3) void gemm_f16(
    const f16* __restrict__ A, const f16* __restrict__ B,
    float* __restrict__ Cf, f16* __restrict__ Cq, f16* __restrict__ Ck,
    f16* __restrict__ Cv, int M, int N, int K,
    const float* __restrict__ kvp, const int* __restrict__ layer,
    f16* __restrict__ ckc)
{
    __shared__ f16 As[128 * 64];
    __shared__ f16 Bs[128 * 64];

    const int bx = blockIdx.x;

    if (EPI == 0 && bx >= 384) {
        const int lay = layer[0];
        int base = (bx - 384) * 256 + threadIdx.x;    // 0..32767
#pragma unroll
        for (int pass = 0; pass < 32; ++pass) {
            int i4 = base + pass * 32768;              // 0..1048575
            int half = i4 >> 19;
            int e = (i4 & 524287) * 4;
            int hh = e >> 18, rem = e & 262143, l = rem >> 7, d = rem & 127;
            int blk = l >> 4, rr = l & 15;
            size_t src = (((size_t)(lay * 2 + half) * 256 + blk) * 8 + hh) * 2048
                       + (size_t)rr * 128 + d;
            f32x4 x = *(const f32x4*)(kvp + src);
            f16x4 h;
#pragma unroll
            for (int j = 0; j < 4; j++) h[j] = (f16)x[j];
            size_t dst = ((size_t)hh * LCTX + l) * 128 + d;
            *(f16x4*)((half ? Cv : ckc) + dst) = h;
        }
        return;
    }

    const int t = threadIdx.x, lane = t & 63, w = t >> 6;
    const int wm = w >> 1, wn = w & 1;
    const int l16 = lane & 15, g16 = lane >> 4;
    const int nx = (EPI == 0) ? 48 : 32;
    const int m0 = (bx / nx) * 128, n0 = (bx % nx) * 128;

    const int srow = lane >> 3;
    const int sgr  = (lane & 7) ^ srow;

    const size_t aoff = (size_t)(m0 + w * 32 + srow) * K + sgr * 8;
    const size_t boff = (size_t)(n0 + w * 32 + srow) * K + sgr * 8;

    f32x4 acc[4][4];
#pragma unroll
    for (int i = 0; i < 4; i++)
#pragma unroll
        for (int j = 0; j < 4; j++) acc[i][j] = (f32x4){0.f, 0.f, 0.f, 0.f};

    for (int k0 = 0; k0 < K; k0 += 64) {
#pragma unroll
        for (int j = 0; j < 4; j++) {
            gl_lds16(A + aoff + (size_t)j * 8 * K + k0, (void*)(As + (w * 32 + j * 8) * 64));
            gl_lds16(B + boff + (size_t)j * 8 * K + k0, (void*)(Bs + (w * 32 + j * 8) * 64));
        }
        __syncthreads();

#pragma unroll
        for (int ks = 0; ks < 2; ks++) {
            f16x8 af[4], bfr[4];
#pragma unroll
            for (int mi = 0; mi < 4; mi++) {
                int r = wm * 64 + mi * 16 + l16;
                int g = ks * 4 + g16;
                af[mi] = *(const f16x8*)&As[r * 64 + ((g ^ (r & 7)) << 3)];
            }
#pragma unroll
            for (int ni = 0; ni < 4; ni++) {
                int r = wn * 64 + ni * 16 + l16;
                int g = ks * 4 + g16;
                bfr[ni] = *(const f16x8*)&Bs[r * 64 + ((g ^ (r & 7)) << 3)];
            }
#pragma unroll
            for (int ni = 0; ni < 4; ni++)
#pragma unroll
                for (int mi = 0; mi < 4; mi++)
                    acc[mi][ni] = mfma16(af[mi], bfr[ni], acc[mi][ni]);
        }
        __syncthreads();
    }

#pragma unroll
    for (int mi = 0; mi < 4; mi++)
#pragma unroll
        for (int ni = 0; ni < 4; ni++)
#pragma unroll
            for (int r = 0; r < 4; r++) {
                int row = m0 + wm * 64 + mi * 16 + (g16 << 2) + r;
                int col = n0 + wn * 64 + ni * 16 + l16;
                float val = acc[mi][ni][r];
                if (EPI == 0) {
                    if (col < 4096) {
                        Cq[(size_t)row * 4096 + col] = (f16)val;
                    } else if (col < 5120) {
                        Ck[(size_t)row * 1024 + (col - 4096)] = (f16)val;
                    } else {
                        int c = col - 5120;
                        int hh = c >> 7, d = c & 127;
                        Cv[((size_t)hh * LCTX + PASTN + row) * 128 + d] = (f16)val;
                    }
                } else {
                    Cf[(size_t)row * N + col] = val;
                }
            }
}

// ---------------------------------------------------------------------------
// aux2: Wo cvt (4,194,304 f4) + rope_q (262,144) + rope_k (65,536)
// = 4,521,984 = 17664 x 256.
// ---------------------------------------------------------------------------
__global__ void aux2(const float* __restrict__ Wo, f16* __restrict__ w16,
                     f16* __restrict__ q16, const f16* __restrict__ kraw,
                     const float* __restrict__ cosp, const float* __restrict__ sinp,
                     f16* __restrict__ ck)
{
    int i = blockIdx.x * 256 + threadIdx.x;
    if (i < 4194304) {
        f32x4 v = *(const f32x4*)(Wo + (size_t)i * 4);
        f16x4 h;
#pragma unroll
        for (int j = 0; j < 4; j++) h[j] = (f16)v[j];
        *(f16x4*)(w16 + (size_t)i * 4) = h;
    } else if (i < 4456448) {
        int ii = i - 4194304;
        int gd = ii & 7, hh = (ii >> 3) & 31, s = ii >> 8;
        size_t b1 = (size_t)s * 4096 + hh * 128 + gd * 8;
        f16x8 x1 = *(f16x8*)(q16 + b1);
        f16x8 x2 = *(f16x8*)(q16 + b1 + 64);
        const float* c1 = cosp + s * 128 + gd * 8;
        const float* s1 = sinp + s * 128 + gd * 8;
        f16x8 o1, o2;
#pragma unroll
        for (int j = 0; j < 8; j++) {
            float a = (float)x1[j], b = (float)x2[j];
            o1[j] = (f16)((a * c1[j] - b * s1[j]) * QK_SCALE_LOG2);
            o2[j] = (f16)((b * c1[j + 64] + a * s1[j + 64]) * QK_SCALE_LOG2);
        }
        *(f16x8*)(q16 + b1) = o1;
        *(f16x8*)(q16 + b1 + 64) = o2;
    } else {
        int ii = i - 4456448;
        int gd = ii & 7, kvh = (ii >> 3) & 7, s = ii >> 6;
        size_t b1 = (size_t)s * 1024 + kvh * 128 + gd * 8;
        f16x8 x1 = *(const f16x8*)(kraw + b1);
        f16x8 x2 = *(const f16x8*)(kraw + b1 + 64);
        const float* c1 = cosp + s * 128 + gd * 8;
        const float* s1 = sinp + s * 128 + gd * 8;
        f16x8 o1, o2;
#pragma unroll
        for (int j = 0; j < 8; j++) {
            float a = (float)x1[j], b = (float)x2[j];
            o1[j] = (f16)(a * c1[j] - b * s1[j]);
            o2[j] = (f16)(b * c1[j + 64] + a * s1[j + 64]);
        }
        size_t dst = ((size_t)kvh * LCTX + PASTN + s) * 128 + gd * 8;
        *(f16x8*)(ck + dst) = o1;
        *(f16x8*)(ck + dst + 64) = o2;
    }
}

// ---------------------------------------------------------------------------
// Flash attention PARTIAL: 4-way KV-split, KVBLK=32, 4 blocks/CU.
// Grid 1024: z=b>>8 (0..3), idx=b&255, h=idx&31, jj=idx>>5,
// j = (z&1) ? 7-jj : jj  (CU pairing: per-CU tile sum = 82), s0=j*128.
// Block z processes kv tiles it = z, z+4, ... (ntt = 68+4j -> 17+j each).
// 4 waves x 32 q-rows (2 groups of 16). LDS: K dbuf 16KB + V dbuf 16KB.
// V region layout: region r = cf*2+ni (512B, [16kv x 16d] tr_b16 subtile);
// staged by 8 gl_lds16 (wave w, q<2 -> regions 2p,2p+1, p=w*2+q).
// ---------------------------------------------------------------------------
__global__ __launch_bounds__(256, 4) void attn_part(
    const f16* __restrict__ Q, const f16* __restrict__ Kc,
    const f16* __restrict__ Vc, f16* __restrict__ Op0, f16* __restrict__ Op1,
    f16* __restrict__ Op2, f16* __restrict__ Op3,
    float* __restrict__ mlb_m, float* __restrict__ mlb_l)
{
    const int b = blockIdx.x;
    const int z = b >> 8;
    const int idx = b & 255;
    const int h = idx & 31;
    const int jj = idx >> 5;
    const int j = (z & 1) ? (7 - jj) : jj;
    const int s0 = j * 128;
    const int kvh = h >> 2;
    const int t = threadIdx.x, lane = t & 63, w = t >> 6;
    const int l16 = lane & 15, g16 = lane >> 4;

    __shared__ f16 Ks[2][32 * 128];
    __shared__ f16 Vs[2][32 * 128];

    f16* Op = (z == 0) ? Op0 : (z == 1) ? Op1 : (z == 2) ? Op2 : Op3;

    // Q fragments, two groups: rows = s0 + w*32 + {0,16} + l16
    f16x8 qfA[4], qfB[4];
    {
        size_t baseA = (size_t)(s0 + w * 32 + l16) * 4096 + h * 128;
        size_t baseB = baseA + (size_t)16 * 4096;
#pragma unroll
        for (int kk = 0; kk < 4; kk++) {
            qfA[kk] = *(const f16x8*)(Q + baseA + kk * 32 + g16 * 8);
            qfB[kk] = *(const f16x8*)(Q + baseB + kk * 32 + g16 * 8);
        }
    }

    f32x4 ofA[8], ofB[8];
#pragma unroll
    for (int cf = 0; cf < 8; cf++) {
        ofA[cf] = (f32x4){0.f, 0.f, 0.f, 0.f};
        ofB[cf] = (f32x4){0.f, 0.f, 0.f, 0.f};
    }
    f32x4 lsA = (f32x4){0.f, 0.f, 0.f, 0.f};
    f32x4 lsB = (f32x4){0.f, 0.f, 0.f, 0.f};
    float mrA = -3.0e38f, mrB = -3.0e38f;
    const f16x4 vone = {(f16)1.f, (f16)1.f, (f16)1.f, (f16)1.f};

    const f16* Kb = Kc + (size_t)kvh * LCTX * 128;
    const f16* Vb = Vc + (size_t)kvh * LCTX * 128;
    const int ntt = (PASTN + s0 + 128) >> 5;     // 68 + 4j (divisible by 4)

    // K staging: load L = w*2+q covers rows L*4..L*4+3 (1KB each)
    const int krow = lane >> 4;                  // 0..3
    const int kp   = lane & 15;
    // V staging: load p = w*2+q -> regions 2p (lanes 0..31, ni=0), 2p+1 (ni=1)
    const int lh  = lane & 31;
    const int niv = lane >> 5;
    const int vr  = 4 * (lh >> 3) + ((lh >> 1) & 3);   // kv-row within 16
    const int vcl = 8 * (lh & 1);                      // d sub-offset

    const uint32_t vs0 = lds_lo(Vs[0]) + lane * 8;
    const uint32_t vs1 = lds_lo(Vs[1]) + lane * 8;

#define STAGE_KV(l0, buf)                                                     \
    {                                                                         \
        _Pragma("unroll")                                                     \
        for (int q = 0; q < 2; q++) {                                         \
            int L = w * 2 + q;                                                \
            int r7 = ((L & 1) << 2) + krow;                                   \
            int sg = kp ^ r7;                                                 \
            gl_lds16(Kb + (size_t)((l0) + L * 4 + krow) * 128 + sg * 8,       \
                     (void*)(Ks[buf] + (L * 4) * 128));                       \
        }                                                                     \
        _Pragma("unroll")                                                     \
        for (int q = 0; q < 2; q++) {                                         \
            int p = w * 2 + q;                                                \
            gl_lds16(Vb + (size_t)((l0) + niv * 16 + vr) * 128 + p * 16 + vcl,\
                     (void*)(Vs[buf] + p * 512));                             \
        }                                                                     \
    }

    STAGE_KV(z * 32, 0);
    __syncthreads();

    int itp = 0;
    for (int it = z; it < ntt; it += 4, ++itp) {
        const int l0 = it << 5;
        const int cur = itp & 1;

        if (it + 4 < ntt) STAGE_KV(l0 + 128, cur ^ 1);

        // ---- S^T = K Q^T for both q-groups (16 x32-MFMA) ----
        f32x4 sA[2], sB[2];
#pragma unroll
        for (int ni = 0; ni < 2; ni++) {
            sA[ni] = (f32x4){0.f, 0.f, 0.f, 0.f};
            sB[ni] = (f32x4){0.f, 0.f, 0.f, 0.f};
        }
        __builtin_amdgcn_s_setprio(1);
#pragma unroll
        for (int ni = 0; ni < 2; ni++)
#pragma unroll
            for (int kk = 0; kk < 4; kk++) {
                int r = ni * 16 + l16;
                int g = kk * 4 + g16;
                f16x8 kh = *(const f16x8*)&Ks[cur][r * 128 + ((g ^ (r & 7)) << 3)];
                sA[ni] = mfma16(kh, qfA[kk], sA[ni]);
                sB[ni] = mfma16(kh, qfB[kk], sB[ni]);
            }
        __builtin_amdgcn_s_setprio(0);

        // ---- masking + lane-local softmax (log2 domain) ----
#define SOFTMAX(sf, mr, ls, of, QOFF)                                          \
        {                                                                      \
            const int qrow = s0 + w * 32 + (QOFF) + l16;                       \
            if (l0 + 31 > PASTN + s0 + w * 32 + (QOFF)) {                      \
                _Pragma("unroll")                                              \
                for (int ni = 0; ni < 2; ni++)                                 \
                    _Pragma("unroll")                                          \
                    for (int r = 0; r < 4; r++) {                              \
                        int col = l0 + ni * 16 + (g16 << 2) + r;               \
                        if (col > PASTN + qrow) sf[ni][r] = -3.0e38f;          \
                    }                                                          \
            }                                                                  \
            float mx;                                                          \
            {                                                                  \
                f32x4 m4 = sf[0];                                              \
                m4[0] = fmaxf(m4[0], sf[1][0]);                                \
                m4[1] = fmaxf(m4[1], sf[1][1]);                                \
                m4[2] = fmaxf(m4[2], sf[1][2]);                                \
                m4[3] = fmaxf(m4[3], sf[1][3]);                                \
                mx = fmaxf(fmaxf(m4[0], m4[1]), fmaxf(m4[2], m4[3]));          \
            }                                                                  \
            mx = fmaxf(mx, __shfl_xor(mx, 16));                                \
            mx = fmaxf(mx, __shfl_xor(mx, 32));                                \
            if (__any(mx > mr + RESC_THR)) {                                   \
                float mnew = fmaxf(mr, mx);                                    \
                float corr = exp2f(mr - mnew);                                 \
                mr = mnew;                                                     \
                float cr[4];                                                   \
                _Pragma("unroll")                                              \
                for (int r = 0; r < 4; r++) cr[r] = __shfl(corr, (g16 << 2) + r); \
                _Pragma("unroll")                                              \
                for (int r = 0; r < 4; r++) ls[r] *= cr[r];                    \
                _Pragma("unroll")                                              \
                for (int cf = 0; cf < 8; cf++)                                 \
                    _Pragma("unroll")                                          \
                    for (int r = 0; r < 4; r++) of[cf][r] *= cr[r];            \
            }                                                                  \
            _Pragma("unroll")                                                  \
            for (int ni = 0; ni < 2; ni++)                                     \
                _Pragma("unroll")                                              \
                for (int r = 0; r < 4; r++)                                    \
                    sf[ni][r] = exp2f(sf[ni][r] - mr);                         \
        }

        SOFTMAX(sA, mrA, lsA, ofA, 0)
        SOFTMAX(sB, mrB, lsB, ofB, 16)

        // ---- P fragments ----
        f16x4 paA[2], paB[2];
#pragma unroll
        for (int ni = 0; ni < 2; ni++) {
            paA[ni][0] = (f16)sA[ni][0]; paA[ni][1] = (f16)sA[ni][1];
            paA[ni][2] = (f16)sA[ni][2]; paA[ni][3] = (f16)sA[ni][3];
            paB[ni][0] = (f16)sB[ni][0]; paB[ni][1] = (f16)sB[ni][1];
            paB[ni][2] = (f16)sB[ni][2]; paB[ni][3] = (f16)sB[ni][3];
        }

        // ---- O += P@V (16 tr-reads x 2 groups), lsum += P@1 ----
        {
            const uint32_t va = cur ? vs1 : vs0;
            f16x4 ra0, ra1, ra2, ra3, rb0, rb1, rb2, rb3;
            f16x4 rc0, rc1, rc2, rc3, rd0, rd1, rd2, rd3;
            __builtin_amdgcn_s_setprio(1);
            TRRD(ra0,va,0);     TRRD(ra1,va,512);   TRRD(ra2,va,1024);  TRRD(ra3,va,1536);
            TRRD(rb0,va,2048);  TRRD(rb1,va,2560);  TRRD(rb2,va,3072);  TRRD(rb3,va,3584);
#pragma unroll
            for (int ni = 0; ni < 2; ni++) {
                lsA = mfma16k16(paA[ni], vone, lsA);
                lsB = mfma16k16(paB[ni], vone, lsB);
            }
#define X2(cf, ni, reg) \
            ofA[cf] = mfma16k16(paA[ni], reg, ofA[cf]); \
            ofB[cf] = mfma16k16(paB[ni], reg, ofB[cf]);
            WAITL(4);
            X2(0,0,ra0) X2(0,1,ra1) X2(1,0,ra2) X2(1,1,ra3)
            TRRD(rc0,va,4096);  TRRD(rc1,va,4608);  TRRD(rc2,va,5120);  TRRD(rc3,va,5632);
            WAITL(4);
            X2(2,0,rb0) X2(2,1,rb1) X2(3,0,rb2) X2(3,1,rb3)
            TRRD(rd0,va,6144);  TRRD(rd1,va,6656);  TRRD(rd2,va,7168);  TRRD(rd3,va,7680);
            WAITL(4);
            X2(4,0,rc0) X2(4,1,rc1) X2(5,0,rc2) X2(5,1,rc3)
            WAITL(0);
            X2(6,0,rd0) X2(6,1,rd1) X2(7,0,rd2) X2(7,1,rd3)
#undef X2
            __builtin_amdgcn_s_setprio(0);
        }
        __syncthreads();
    }

    // ---- write partial O (normalized by lsum) + m + l ----
#define WRITE_P(of, mr, ls, QOFF)                                             \
    {                                                                         \
        if (lane < 16) {                                                      \
            int srow = s0 + w * 32 + (QOFF) + lane;                           \
            mlb_m[((size_t)z * 1024 + srow) * 32 + h] = mr;                   \
        }                                                                     \
        if (l16 == 0) {                                                       \
            _Pragma("unroll")                                                 \
            for (int r = 0; r < 4; r++) {                                     \
                int srow = s0 + w * 32 + (QOFF) + (g16 << 2) + r;             \
                mlb_l[((size_t)z * 1024 + srow) * 32 + h] = ls[r];            \
            }                                                                 \
        }                                                                     \
        _Pragma("unroll")                                                     \
        for (int cf = 0; cf < 8; cf++)                                        \
            _Pragma("unroll")                                                 \
            for (int r = 0; r < 4; r++) {                                     \
                int srow = s0 + w * 32 + (QOFF) + (g16 << 2) + r;             \
                int d = cf * 16 + l16;                                        \
                Op[(size_t)srow * 4096 + (size_t)h * 128 + d] =               \
                    (f16)(of[cf][r] / ls[r]);                                 \
            }                                                                 \
    }
    WRITE_P(ofA, mrA, lsA, 0)
    WRITE_P(ofB, mrB, lsB, 16)
#undef WRITE_P
#undef SOFTMAX
#undef STAGE_KV
}

// ---------------------------------------------------------------------------
// combine (in place into Op0): Op0 = sum_i(Oi*li*wi) / sum_i(li*wi),
// wi = 2^(mi - m*). Element-wise per (s,h,d) -> in-place write is safe.
// ---------------------------------------------------------------------------
__global__ void attn_combine(f16* Op0, const f16* Op1, const f16* Op2,
                             const f16* Op3, const float* mlb_m,
                             const float* mlb_l)
{
    int i = blockIdx.x * 256 + threadIdx.x;
    int d8 = i & 15, hh = (i >> 4) & 31, s = i >> 9;
    float m[4], l[4];
#pragma unroll
    for (int zz = 0; zz < 4; zz++) {
        m[zz] = mlb_m[((size_t)zz * 1024 + s) * 32 + hh];
        l[zz] = mlb_l[((size_t)zz * 1024 + s) * 32 + hh];
    }
    float mstar = fmaxf(fmaxf(m[0], m[1]), fmaxf(m[2], m[3]));
    float wt[4];
    float tot = 0.f;
#pragma unroll
    for (int zz = 0; zz < 4; zz++) { wt[zz] = exp2f(m[zz] - mstar) * l[zz]; tot += wt[zz]; }
    float inv = 1.0f / tot;
    size_t off = (size_t)s * 4096 + (size_t)hh * 128 + d8 * 8;
    f16x8 a0 = *(const f16x8*)(Op0 + off);
    f16x8 a1 = *(const f16x8*)(Op1 + off);
    f16x8 a2 = *(const f16x8*)(Op2 + off);
    f16x8 a3 = *(const f16x8*)(Op3 + off);
    f16x8 o;
#pragma unroll
    for (int jx = 0; jx < 8; jx++)
        o[jx] = (f16)(((float)a0[jx] * wt[0] + (float)a1[jx] * wt[1]
                     + (float)a2[jx] * wt[2] + (float)a3[jx] * wt[3]) * inv);
    *(f16x8*)(Op0 + off) = o;
}

// ---------------------------------------------------------------------------
// launcher
// ---------------------------------------------------------------------------
extern "C" void kernel_launch(void* const* d_in, const int* in_sizes, int n_in,
                              void* d_out, int out_size, void* d_ws, size_t ws_size,
                              hipStream_t stream)
{
    const float* hidden = (const float*)d_in[0];
    const float* kvp    = (const float*)d_in[1];
    const float* cosp   = (const float*)d_in[7];
    const float* sinp   = (const float*)d_in[8];
    const float* Wq     = (const float*)d_in[9];
    const float* Wk     = (const float*)d_in[10];
    const float* Wv     = (const float*)d_in[11];
    const float* Wo     = (const float*)d_in[12];
    const int*   layer  = (const int*)d_in[13];

    char* ws = (char*)d_ws;
    // ws map (proven <= 76 MB):
    //  [0,48)   w16: Wq|Wk|Wv f16; after aux2 [0,32) holds Wo f16
    //  [32,40)  opart0 (dead Wk region; also combine output; o-proj A)
    //  [40,48)  opart1 (dead Wv region)
    //  [48,56)  h16 (hidden f16) -> opart2 after QKV gemm
    //  [56,62)  ck (K cache f16)
    //  [62,68)  cv (V cache f16)
    //  [68,76)  opart3
    f16* w16    = (f16*)ws;
    f16* opart0 = (f16*)(ws + 33554432);
    f16* opart1 = (f16*)(ws + 41943040);
    f16* h16    = (f16*)(ws + 50331648);
    f16* opart2 = (f16*)(ws + 50331648);
    f16* ck     = (f16*)(ws + 58720256);
    f16* cv     = (f16*)(ws + 65011712);
    f16* opart3 = (f16*)(ws + 71303168);

    f16*   q16   = (f16*)d_out;                      // d_out[0,8MB)
    f16*   kraw  = (f16*)((char*)d_out + 8388608);   // d_out[8,10MB); dead after aux2
    float* mlb_m = (float*)((char*)d_out + 8388608); // 512 KB (over kraw)
    float* mlb_l = (float*)((char*)d_out + 8912896); // 512 KB

    // 1) fp32 -> fp16 conversions (hidden + Wq + Wk + Wv)
    cvt_all<<<28672, 256, 0, stream>>>(hidden, Wq, Wk, Wv, h16, w16);

    // 2) fused QKV projection + cached-KV convert (512 blocks = 2/CU exact)
    gemm_f16<0><<<dim3(512), 256, 0, stream>>>(
        h16, w16, nullptr, q16, kraw, cv, 1024, 6144, 4096, kvp, layer, ck);

    // 3) Wo cvt + RoPE q/k
    aux2<<<17664, 256, 0, stream>>>(Wo, w16, q16, kraw, cosp, sinp, ck);

    // 4) flash attention partial (1024 blocks, 4-way KV-split, 4 blocks/CU)
    attn_part<<<dim3(1024), 256, 0, stream>>>(
        q16, ck, cv, opart0, opart1, opart2, opart3, mlb_m, mlb_l);

    // 5) combine partials (in place into opart0)
    attn_combine<<<2048, 256, 0, stream>>>(opart0, opart1, opart2, opart3,
                                           mlb_m, mlb_l);

    // 6) output projection: A = opart0 -> d_out fp32
    gemm_f16<1><<<dim3(256), 256, 0, stream>>>(
        opart0, w16, (float*)d_out, nullptr, nullptr, nullptr, 1024, 4096, 4096,
        nullptr, nullptr, nullptr);
}

// Round 13
// 274.000 us; speedup vs baseline: 1.5878x; 1.5878x over previous
//
#include <hip/hip_runtime.h>
#include <cstdint>
#include <cstddef>

// ---------------------------------------------------------------------------
// L4maAttention, fp16 pipeline (round 13):
//   cvt_all -> gemm<0,BM=128> (384 GEMM + 128 cache-conv = 512 blocks, 2/CU)
//   -> aux2 (Wo cvt + RoPE q/k) ->
//   attn_part (round-10 exact: KV-split z=0/1, KVBLK=64, 32 q/wave,
//              launch_bounds(256,2), lane-local softmax, x16-MFMA PV) ->
//   combine -> gemm<1,BM=64> O-proj (512 blocks = 2/CU, split-M) -> fp32.
// ---------------------------------------------------------------------------

typedef _Float16 f16;
typedef f16 f16x8 __attribute__((ext_vector_type(8)));
typedef f16 f16x4 __attribute__((ext_vector_type(4)));
typedef float f32x4 __attribute__((ext_vector_type(4)));

#define HIDN 4096
#define LCTX 3072
#define PASTN 2048
#define QK_SCALE_LOG2 0.12753102734366334f
#define RESC_THR 11.54f

__device__ __forceinline__ f32x4 mfma16(f16x8 a, f16x8 b, f32x4 c) {
    return __builtin_amdgcn_mfma_f32_16x16x32_f16(a, b, c, 0, 0, 0);
}
__device__ __forceinline__ f32x4 mfma16k16(f16x4 a, f16x4 b, f32x4 c) {
    return __builtin_amdgcn_mfma_f32_16x16x16f16(a, b, c, 0, 0, 0);
}

__device__ __forceinline__ void gl_lds16(const void* g, void* l) {
    auto gp = (const __attribute__((address_space(1))) unsigned int*)(uintptr_t)g;
    auto lp = (__attribute__((address_space(3))) unsigned int*)(uintptr_t)l;
    __builtin_amdgcn_global_load_lds(gp, lp, 16, 0, 0);
}

__device__ __forceinline__ uint32_t lds_lo(const void* p) {
    return (uint32_t)(uintptr_t)p;
}

#define TRRD(dst, va, OFF) \
    asm volatile("ds_read_b64_tr_b16 %0, %1 offset:" #OFF : "=v"(dst) : "v"(va))
#define WAITL(N) \
    asm volatile("s_waitcnt lgkmcnt(" #N ")" ::: "memory"); \
    __builtin_amdgcn_sched_barrier(0)

// ---------------------------------------------------------------------------
// cvt_all: hidden (1M f4) + Wq (4M) + Wk (1M) + Wv (1M) = 7,340,032 = 28672x256
// ---------------------------------------------------------------------------
__global__ void cvt_all(const float* __restrict__ hidden, const float* __restrict__ Wq,
                        const float* __restrict__ Wk, const float* __restrict__ Wv,
                        f16* __restrict__ h16, f16* __restrict__ w16)
{
    int i = blockIdx.x * 256 + threadIdx.x;
    const float* src; f16* dst; int off;
    if (i < 1048576)      { src = hidden; dst = h16; off = i; }
    else if (i < 5242880) { src = Wq; dst = w16; off = i - 1048576; }
    else if (i < 6291456) { src = Wk; dst = w16 + (size_t)4096 * 4096; off = i - 5242880; }
    else                  { src = Wv; dst = w16 + (size_t)5120 * 4096; off = i - 6291456; }
    f32x4 v = *(const f32x4*)(src + (size_t)off * 4);
    f16x4 h;
#pragma unroll
    for (int j = 0; j < 4; j++) h[j] = (f16)v[j];
    *(f16x4*)(dst + (size_t)off * 4) = h;
}

// ---------------------------------------------------------------------------
// GEMM (+fused cache_conv for EPI 0): C[M,N] = A[M,K] @ B[N,K]^T, fp16.
// BM: output tile rows (128 QKV / 64 o-proj).
// EPI 0 (BM=128): grid 512: blocks 0..383 GEMM (48x8 tiles of 128x128),
//   384..511 cached-KV convert (32 passes each) -> 2 blocks/CU exact.
// EPI 1 (BM=64): grid 512 (32x16 tiles of 128x64), fp32 C -> 2 blocks/CU.
// ---------------------------------------------------------------------------
template <int EPI, int BM>
__global__ __launch_bounds__(256, 3) void gemm_f16(
    const f16* __restrict__ A, const f16* __restrict__ B,
    float* __restrict__ Cf, f16* __restrict__ Cq, f16* __restrict__ Ck,
    f16* __restrict__ Cv, int M, int N, int K,
    const float* __restrict__ kvp, const int* __restrict__ layer,
    f16* __restrict__ ckc)
{
    __shared__ f16 As[BM * 64];
    __shared__ f16 Bs[128 * 64];

    const int bx = blockIdx.x;

    if (EPI == 0 && bx >= 384) {
        const int lay = layer[0];
        int base = (bx - 384) * 256 + threadIdx.x;    // 0..32767
#pragma unroll
        for (int pass = 0; pass < 32; ++pass) {
            int i4 = base + pass * 32768;              // 0..1048575
            int half = i4 >> 19;
            int e = (i4 & 524287) * 4;
            int hh = e >> 18, rem = e & 262143, l = rem >> 7, d = rem & 127;
            int blk = l >> 4, rr = l & 15;
            size_t src = (((size_t)(lay * 2 + half) * 256 + blk) * 8 + hh) * 2048
                       + (size_t)rr * 128 + d;
            f32x4 x = *(const f32x4*)(kvp + src);
            f16x4 h;
#pragma unroll
            for (int j = 0; j < 4; j++) h[j] = (f16)x[j];
            size_t dst = ((size_t)hh * LCTX + l) * 128 + d;
            *(f16x4*)((half ? Cv : ckc) + dst) = h;
        }
        return;
    }

    constexpr int RPW = BM / 4;        // staged rows per wave
    constexpr int MI  = BM / 32;       // acc row-fragments per wave half

    const int t = threadIdx.x, lane = t & 63, w = t >> 6;
    const int wm = w >> 1, wn = w & 1;
    const int l16 = lane & 15, g16 = lane >> 4;
    const int nx = (EPI == 0) ? 48 : 32;
    const int m0 = (bx / nx) * BM, n0 = (bx % nx) * 128;

    const int srow = lane >> 3;
    const int sgr  = (lane & 7) ^ srow;

    const size_t aoff = (size_t)(m0 + w * RPW + srow) * K + sgr * 8;
    const size_t boff = (size_t)(n0 + w * 32 + srow) * K + sgr * 8;

    f32x4 acc[MI][4];
#pragma unroll
    for (int i = 0; i < MI; i++)
#pragma unroll
        for (int j = 0; j < 4; j++) acc[i][j] = (f32x4){0.f, 0.f, 0.f, 0.f};

    for (int k0 = 0; k0 < K; k0 += 64) {
#pragma unroll
        for (int j = 0; j < RPW / 8; j++)
            gl_lds16(A + aoff + (size_t)j * 8 * K + k0,
                     (void*)(As + (w * RPW + j * 8) * 64));
#pragma unroll
        for (int j = 0; j < 4; j++)
            gl_lds16(B + boff + (size_t)j * 8 * K + k0,
                     (void*)(Bs + (w * 32 + j * 8) * 64));
        __syncthreads();

#pragma unroll
        for (int ks = 0; ks < 2; ks++) {
            f16x8 af[MI], bfr[4];
#pragma unroll
            for (int mi = 0; mi < MI; mi++) {
                int r = wm * (BM / 2) + mi * 16 + l16;
                int g = ks * 4 + g16;
                af[mi] = *(const f16x8*)&As[r * 64 + ((g ^ (r & 7)) << 3)];
            }
#pragma unroll
            for (int ni = 0; ni < 4; ni++) {
                int r = wn * 64 + ni * 16 + l16;
                int g = ks * 4 + g16;
                bfr[ni] = *(const f16x8*)&Bs[r * 64 + ((g ^ (r & 7)) << 3)];
            }
#pragma unroll
            for (int ni = 0; ni < 4; ni++)
#pragma unroll
                for (int mi = 0; mi < MI; mi++)
                    acc[mi][ni] = mfma16(af[mi], bfr[ni], acc[mi][ni]);
        }
        __syncthreads();
    }

#pragma unroll
    for (int mi = 0; mi < MI; mi++)
#pragma unroll
        for (int ni = 0; ni < 4; ni++)
#pragma unroll
            for (int r = 0; r < 4; r++) {
                int row = m0 + wm * (BM / 2) + mi * 16 + (g16 << 2) + r;
                int col = n0 + wn * 64 + ni * 16 + l16;
                float val = acc[mi][ni][r];
                if (EPI == 0) {
                    if (col < 4096) {
                        Cq[(size_t)row * 4096 + col] = (f16)val;
                    } else if (col < 5120) {
                        Ck[(size_t)row * 1024 + (col - 4096)] = (f16)val;
                    } else {
                        int c = col - 5120;
                        int hh = c >> 7, d = c & 127;
                        Cv[((size_t)hh * LCTX + PASTN + row) * 128 + d] = (f16)val;
                    }
                } else {
                    Cf[(size_t)row * N + col] = val;
                }
            }
}

// ---------------------------------------------------------------------------
// aux2: Wo cvt (4,194,304 f4) + rope_q (262,144) + rope_k (65,536)
// = 4,521,984 = 17664 x 256.
// ---------------------------------------------------------------------------
__global__ void aux2(const float* __restrict__ Wo, f16* __restrict__ w16,
                     f16* __restrict__ q16, const f16* __restrict__ kraw,
                     const float* __restrict__ cosp, const float* __restrict__ sinp,
                     f16* __restrict__ ck)
{
    int i = blockIdx.x * 256 + threadIdx.x;
    if (i < 4194304) {
        f32x4 v = *(const f32x4*)(Wo + (size_t)i * 4);
        f16x4 h;
#pragma unroll
        for (int j = 0; j < 4; j++) h[j] = (f16)v[j];
        *(f16x4*)(w16 + (size_t)i * 4) = h;
    } else if (i < 4456448) {
        int ii = i - 4194304;
        int gd = ii & 7, hh = (ii >> 3) & 31, s = ii >> 8;
        size_t b1 = (size_t)s * 4096 + hh * 128 + gd * 8;
        f16x8 x1 = *(f16x8*)(q16 + b1);
        f16x8 x2 = *(f16x8*)(q16 + b1 + 64);
        const float* c1 = cosp + s * 128 + gd * 8;
        const float* s1 = sinp + s * 128 + gd * 8;
        f16x8 o1, o2;
#pragma unroll
        for (int j = 0; j < 8; j++) {
            float a = (float)x1[j], b = (float)x2[j];
            o1[j] = (f16)((a * c1[j] - b * s1[j]) * QK_SCALE_LOG2);
            o2[j] = (f16)((b * c1[j + 64] + a * s1[j + 64]) * QK_SCALE_LOG2);
        }
        *(f16x8*)(q16 + b1) = o1;
        *(f16x8*)(q16 + b1 + 64) = o2;
    } else {
        int ii = i - 4456448;
        int gd = ii & 7, kvh = (ii >> 3) & 7, s = ii >> 6;
        size_t b1 = (size_t)s * 1024 + kvh * 128 + gd * 8;
        f16x8 x1 = *(const f16x8*)(kraw + b1);
        f16x8 x2 = *(const f16x8*)(kraw + b1 + 64);
        const float* c1 = cosp + s * 128 + gd * 8;
        const float* s1 = sinp + s * 128 + gd * 8;
        f16x8 o1, o2;
#pragma unroll
        for (int j = 0; j < 8; j++) {
            float a = (float)x1[j], b = (float)x2[j];
            o1[j] = (f16)(a * c1[j] - b * s1[j]);
            o2[j] = (f16)(b * c1[j + 64] + a * s1[j + 64]);
        }
        size_t dst = ((size_t)kvh * LCTX + PASTN + s) * 128 + gd * 8;
        *(f16x8*)(ck + dst) = o1;
        *(f16x8*)(ck + dst + 64) = o2;
    }
}

// ---------------------------------------------------------------------------
// Flash attention PARTIAL (round-10 exact): 2-way KV-split, KVBLK=64.
// Grid 512: z=b>>8, idx=b&255, h=idx&31, jj=idx>>5, j = z?7-jj:jj, s0=j*128.
// Block z processes kv tiles it=z,z+2,...; 4 waves x 32 q (2 groups of 16).
// ---------------------------------------------------------------------------
__global__ __launch_bounds__(256, 2) void attn_part(
    const f16* __restrict__ Q, const f16* __restrict__ Kc,
    const f16* __restrict__ Vc, f16* __restrict__ Op, float* __restrict__ mlb)
{
    const int b = blockIdx.x;
    const int z = b >> 8;
    const int idx = b & 255;
    const int h = idx & 31;
    const int jj = idx >> 5;
    const int j = z ? (7 - jj) : jj;
    const int s0 = j * 128;
    const int kvh = h >> 2;
    const int t = threadIdx.x, lane = t & 63, w = t >> 6;
    const int l16 = lane & 15, g16 = lane >> 4;

    __shared__ f16 Ks[2][64 * 128];
    __shared__ f16 Vs[2][64 * 128];

    f16x8 qfA[4], qfB[4];
    {
        size_t baseA = (size_t)(s0 + w * 32 + l16) * 4096 + h * 128;
        size_t baseB = baseA + (size_t)16 * 4096;
#pragma unroll
        for (int kk = 0; kk < 4; kk++) {
            qfA[kk] = *(const f16x8*)(Q + baseA + kk * 32 + g16 * 8);
            qfB[kk] = *(const f16x8*)(Q + baseB + kk * 32 + g16 * 8);
        }
    }

    f32x4 ofA[8], ofB[8];
#pragma unroll
    for (int cf = 0; cf < 8; cf++) {
        ofA[cf] = (f32x4){0.f, 0.f, 0.f, 0.f};
        ofB[cf] = (f32x4){0.f, 0.f, 0.f, 0.f};
    }
    float mrA = -3.0e38f, lrA = 0.f;
    float mrB = -3.0e38f, lrB = 0.f;

    const f16* Kb = Kc + (size_t)kvh * LCTX * 128;
    const f16* Vb = Vc + (size_t)kvh * LCTX * 128;
    const int ntt = (PASTN + s0 + 128) >> 6;    // even

    const int krow = lane >> 4;
    const int kp   = lane & 15;
    const int vrow = ((lane >> 5) << 4) + (((lane >> 3) & 3) << 2) + ((lane >> 1) & 3);
    const int vch  = (lane & 1) << 3;

    const uint32_t vs0 = lds_lo(Vs[0]) + lane * 8;
    const uint32_t vs1 = lds_lo(Vs[1]) + lane * 8;

#define STAGE_KV(l0, buf)                                                     \
    {                                                                         \
        _Pragma("unroll")                                                     \
        for (int jx = 0; jx < 4; jx++) {                                      \
            int r7 = ((jx & 1) << 2) + krow;                                  \
            int sg = kp ^ r7;                                                 \
            gl_lds16(Kb + (size_t)((l0) + w * 16 + jx * 4 + krow) * 128 + sg * 8, \
                     (void*)(Ks[buf] + (w * 16 + jx * 4) * 128));             \
        }                                                                     \
        _Pragma("unroll")                                                     \
        for (int q = 0; q < 4; q++) {                                         \
            gl_lds16(Vb + (size_t)((l0) + (q & 1) * 32 + vrow) * 128          \
                        + (w * 2 + (q >> 1)) * 16 + vch,                      \
                     (void*)(Vs[buf] + (w * 4 + q) * 512));                   \
        }                                                                     \
    }

    STAGE_KV(z * 64, 0);
    __syncthreads();

    int itp = 0;
    for (int it = z; it < ntt; it += 2, ++itp) {
        const int l0 = it << 6;
        const int cur = itp & 1;

        if (it + 2 < ntt) STAGE_KV(l0 + 128, cur ^ 1);

        f32x4 sA[4], sB[4];
#pragma unroll
        for (int ni = 0; ni < 4; ni++) {
            sA[ni] = (f32x4){0.f, 0.f, 0.f, 0.f};
            sB[ni] = (f32x4){0.f, 0.f, 0.f, 0.f};
        }
        __builtin_amdgcn_s_setprio(1);
#pragma unroll
        for (int ni = 0; ni < 4; ni++)
#pragma unroll
            for (int kk = 0; kk < 4; kk++) {
                int r = ni * 16 + l16;
                int g = kk * 4 + g16;
                f16x8 kh = *(const f16x8*)&Ks[cur][r * 128 + ((g ^ (r & 7)) << 3)];
                sA[ni] = mfma16(kh, qfA[kk], sA[ni]);
                sB[ni] = mfma16(kh, qfB[kk], sB[ni]);
            }
        __builtin_amdgcn_s_setprio(0);

#define SOFTMAX(sf, mr, lr, of, QOFF)                                          \
        {                                                                      \
            const int qrow = s0 + w * 32 + (QOFF) + l16;                       \
            if (l0 + 63 > PASTN + s0 + w * 32 + (QOFF)) {                      \
                _Pragma("unroll")                                              \
                for (int ni = 0; ni < 4; ni++)                                 \
                    _Pragma("unroll")                                          \
                    for (int r = 0; r < 4; r++) {                              \
                        int col = l0 + ni * 16 + (g16 << 2) + r;               \
                        if (col > PASTN + qrow) sf[ni][r] = -3.0e38f;          \
                    }                                                          \
            }                                                                  \
            float mx;                                                          \
            {                                                                  \
                f32x4 m4 = sf[0];                                              \
                _Pragma("unroll")                                              \
                for (int ni = 1; ni < 4; ni++) {                               \
                    m4[0] = fmaxf(m4[0], sf[ni][0]);                           \
                    m4[1] = fmaxf(m4[1], sf[ni][1]);                           \
                    m4[2] = fmaxf(m4[2], sf[ni][2]);                           \
                    m4[3] = fmaxf(m4[3], sf[ni][3]);                           \
                }                                                              \
                mx = fmaxf(fmaxf(m4[0], m4[1]), fmaxf(m4[2], m4[3]));          \
            }                                                                  \
            mx = fmaxf(mx, __shfl_xor(mx, 16));                                \
            mx = fmaxf(mx, __shfl_xor(mx, 32));                                \
            if (__any(mx > mr + RESC_THR)) {                                   \
                float mnew = fmaxf(mr, mx);                                    \
                float corr = exp2f(mr - mnew);                                 \
                mr = mnew;                                                     \
                lr *= corr;                                                    \
                float cr[4];                                                   \
                _Pragma("unroll")                                              \
                for (int r = 0; r < 4; r++) cr[r] = __shfl(corr, (g16 << 2) + r); \
                _Pragma("unroll")                                              \
                for (int cf = 0; cf < 8; cf++)                                 \
                    _Pragma("unroll")                                          \
                    for (int r = 0; r < 4; r++) of[cf][r] *= cr[r];            \
            }                                                                  \
            _Pragma("unroll")                                                  \
            for (int ni = 0; ni < 4; ni++)                                     \
                _Pragma("unroll")                                              \
                for (int r = 0; r < 4; r++) {                                  \
                    float p = exp2f(sf[ni][r] - mr);                           \
                    sf[ni][r] = p;                                             \
                    lr += p;                                                   \
                }                                                              \
        }

        SOFTMAX(sA, mrA, lrA, ofA, 0)
        SOFTMAX(sB, mrB, lrB, ofB, 16)

        f16x4 paA[4], paB[4];
#pragma unroll
        for (int ni = 0; ni < 4; ni++) {
            paA[ni][0] = (f16)sA[ni][0]; paA[ni][1] = (f16)sA[ni][1];
            paA[ni][2] = (f16)sA[ni][2]; paA[ni][3] = (f16)sA[ni][3];
            paB[ni][0] = (f16)sB[ni][0]; paB[ni][1] = (f16)sB[ni][1];
            paB[ni][2] = (f16)sB[ni][2]; paB[ni][3] = (f16)sB[ni][3];
        }

        {
            const uint32_t va = cur ? vs1 : vs0;
            f16x4 ra0, ra1, ra2, ra3, rb0, rb1, rb2, rb3;
            f16x4 rc0, rc1, rc2, rc3, rd0, rd1, rd2, rd3;
            __builtin_amdgcn_s_setprio(1);
            TRRD(ra0,va,0);     TRRD(ra1,va,512);   TRRD(ra2,va,1024);  TRRD(ra3,va,1536);
            TRRD(rb0,va,2048);  TRRD(rb1,va,2560);  TRRD(rb2,va,3072);  TRRD(rb3,va,3584);
            TRRD(rc0,va,4096);  TRRD(rc1,va,4608);  TRRD(rc2,va,5120);  TRRD(rc3,va,5632);
#define X2(cf, ni, reg) \
            ofA[cf] = mfma16k16(paA[ni], reg, ofA[cf]); \
            ofB[cf] = mfma16k16(paB[ni], reg, ofB[cf]);
            WAITL(8);
            X2(0,0,ra0) X2(0,1,ra1) X2(0,2,ra2) X2(0,3,ra3)
            TRRD(rd0,va,6144);  TRRD(rd1,va,6656);  TRRD(rd2,va,7168);  TRRD(rd3,va,7680);
            WAITL(8);
            X2(1,0,rb0) X2(1,1,rb1) X2(1,2,rb2) X2(1,3,rb3)
            TRRD(ra0,va,8192);  TRRD(ra1,va,8704);  TRRD(ra2,va,9216);  TRRD(ra3,va,9728);
            WAITL(8);
            X2(2,0,rc0) X2(2,1,rc1) X2(2,2,rc2) X2(2,3,rc3)
            TRRD(rb0,va,10240); TRRD(rb1,va,10752); TRRD(rb2,va,11264); TRRD(rb3,va,11776);
            WAITL(8);
            X2(3,0,rd0) X2(3,1,rd1) X2(3,2,rd2) X2(3,3,rd3)
            TRRD(rc0,va,12288); TRRD(rc1,va,12800); TRRD(rc2,va,13312); TRRD(rc3,va,13824);
            WAITL(8);
            X2(4,0,ra0) X2(4,1,ra1) X2(4,2,ra2) X2(4,3,ra3)
            TRRD(rd0,va,14336); TRRD(rd1,va,14848); TRRD(rd2,va,15360); TRRD(rd3,va,15872);
            WAITL(8);
            X2(5,0,rb0) X2(5,1,rb1) X2(5,2,rb2) X2(5,3,rb3)
            WAITL(4);
            X2(6,0,rc0) X2(6,1,rc1) X2(6,2,rc2) X2(6,3,rc3)
            WAITL(0);
            X2(7,0,rd0) X2(7,1,rd1) X2(7,2,rd2) X2(7,3,rd3)
#undef X2
            __builtin_amdgcn_s_setprio(0);
        }
        __syncthreads();
    }

#define WRITE_P(of, mr, lr, QOFF)                                             \
    {                                                                         \
        float l2 = lr + __shfl_xor(lr, 16);                                   \
        l2 += __shfl_xor(l2, 32);                                             \
        if (lane < 16) {                                                      \
            int srow = s0 + w * 32 + (QOFF) + lane;                           \
            *(float2*)(mlb + (((size_t)z * 1024 + srow) * 32 + h) * 2) =      \
                make_float2(mr, l2);                                          \
        }                                                                     \
        float lrr[4];                                                         \
        _Pragma("unroll")                                                     \
        for (int r = 0; r < 4; r++) lrr[r] = __shfl(l2, (g16 << 2) + r);      \
        _Pragma("unroll")                                                     \
        for (int cf = 0; cf < 8; cf++)                                        \
            _Pragma("unroll")                                                 \
            for (int r = 0; r < 4; r++) {                                     \
                int srow = s0 + w * 32 + (QOFF) + (g16 << 2) + r;             \
                int d = cf * 16 + l16;                                        \
                Op[(size_t)z * 4194304 + (size_t)srow * 4096                  \
                   + (size_t)h * 128 + d] = (f16)(of[cf][r] / lrr[r]);        \
            }                                                                 \
    }
    WRITE_P(ofA, mrA, lrA, 0)
    WRITE_P(ofB, mrB, lrB, 16)
#undef WRITE_P
#undef SOFTMAX
#undef STAGE_KV
}

// ---------------------------------------------------------------------------
// combine: obuf = (O0*l0*w0 + O1*l1*w1) / (l0*w0 + l1*w1), wi = 2^(mi - m*)
// ---------------------------------------------------------------------------
__global__ void attn_combine(const f16* __restrict__ Op, const float* __restrict__ mlb,
                             f16* __restrict__ obuf)
{
    int i = blockIdx.x * 256 + threadIdx.x;
    int d8 = i & 15, hh = (i >> 4) & 31, s = i >> 9;
    float2 ml0 = *(const float2*)(mlb + (((size_t)0 * 1024 + s) * 32 + hh) * 2);
    float2 ml1 = *(const float2*)(mlb + (((size_t)1 * 1024 + s) * 32 + hh) * 2);
    float mstar = fmaxf(ml0.x, ml1.x);
    float w0 = exp2f(ml0.x - mstar) * ml0.y;
    float w1 = exp2f(ml1.x - mstar) * ml1.y;
    float inv = 1.0f / (w0 + w1);
    size_t off = (size_t)s * 4096 + (size_t)hh * 128 + d8 * 8;
    f16x8 a = *(const f16x8*)(Op + off);
    f16x8 b = *(const f16x8*)(Op + 4194304 + off);
    f16x8 o;
#pragma unroll
    for (int jx = 0; jx < 8; jx++)
        o[jx] = (f16)(((float)a[jx] * w0 + (float)b[jx] * w1) * inv);
    *(f16x8*)(obuf + off) = o;
}

// ---------------------------------------------------------------------------
// launcher
// ---------------------------------------------------------------------------
extern "C" void kernel_launch(void* const* d_in, const int* in_sizes, int n_in,
                              void* d_out, int out_size, void* d_ws, size_t ws_size,
                              hipStream_t stream)
{
    const float* hidden = (const float*)d_in[0];
    const float* kvp    = (const float*)d_in[1];
    const float* cosp   = (const float*)d_in[7];
    const float* sinp   = (const float*)d_in[8];
    const float* Wq     = (const float*)d_in[9];
    const float* Wk     = (const float*)d_in[10];
    const float* Wv     = (const float*)d_in[11];
    const float* Wo     = (const float*)d_in[12];
    const int*   layer  = (const int*)d_in[13];

    char* ws = (char*)d_ws;
    f16* w16  = (f16*)ws;                   // 48 MB: Wqkv; Wo cvt reuses [0,32MB)
    f16* opart= (f16*)(ws + 33554432);      // 16 MB: O partials (dead Wk/Wv)
    f16* h16  = (f16*)(ws + 50331648);      //  8 MB: hidden fp16
    f16* ck   = (f16*)(ws + 58720256);      //  6 MB: K cache fp16
    f16* cv   = (f16*)(ws + 65011712);      //  6 MB: V cache fp16
    f16* obuf = (f16*)(ws + 71303168);      //  8 MB: combined attn out

    f16*   q16  = (f16*)d_out;                      // 8 MB scratch in d_out
    f16*   kraw = (f16*)((char*)d_out + 8388608);   // 2 MB; dead after aux2
    float* mlb  = (float*)((char*)d_out + 8388608); // 512 KB (over kraw)

    // 1) fp32 -> fp16 conversions (hidden + Wq + Wk + Wv)
    cvt_all<<<28672, 256, 0, stream>>>(hidden, Wq, Wk, Wv, h16, w16);

    // 2) fused QKV projection + cached-KV convert (512 blocks = 2/CU exact)
    gemm_f16<0, 128><<<dim3(512), 256, 0, stream>>>(
        h16, w16, nullptr, q16, kraw, cv, 1024, 6144, 4096, kvp, layer, ck);

    // 3) Wo cvt + RoPE q/k
    aux2<<<17664, 256, 0, stream>>>(Wo, w16, q16, kraw, cosp, sinp, ck);

    // 4) flash attention partial (512 blocks, KV-split z=0/1, 32 q/wave)
    attn_part<<<dim3(512), 256, 0, stream>>>(q16, ck, cv, opart, mlb);

    // 5) combine partials -> obuf
    attn_combine<<<2048, 256, 0, stream>>>(opart, mlb, obuf);

    // 6) output projection, split-M 64x128 tiles (512 blocks = 2/CU) -> fp32
    gemm_f16<1, 64><<<dim3(512), 256, 0, stream>>>(
        obuf, w16, (float*)d_out, nullptr, nullptr, nullptr, 1024, 4096, 4096,
        nullptr, nullptr, nullptr);
}